// Round 9
// baseline (2024.812 us; speedup 1.0000x reference)
//
#include <hip/hip_runtime.h>
#include <hip/hip_bf16.h>

typedef float f32x4 __attribute__((ext_vector_type(4)));
typedef short s16x8 __attribute__((ext_vector_type(8)));
typedef short s16x4 __attribute__((ext_vector_type(4)));

#define REP_ZB   4
#define REP_ATTN 16

__device__ __forceinline__ unsigned short f2bf(float x){
  unsigned u = __float_as_uint(x);
  u += 0x7fffu + ((u >> 16) & 1u);
  return (unsigned short)(u >> 16);
}
__device__ __forceinline__ float bf2f(unsigned short h){
  return __uint_as_float(((unsigned)h) << 16);
}
__device__ __forceinline__ unsigned pk_bf(float a, float b){
  __hip_bfloat162 t = __float22bfloat162_rn(make_float2(a, b));
  return *reinterpret_cast<unsigned*>(&t);
}

// ---------------- prep: weight transpose->bf16 (0..179), ln_a (180..435), setup (436) ----------------
__global__ __launch_bounds__(256) void prep_kernel(const float* __restrict__ a, const float* __restrict__ ln_a_w,
                             const float* __restrict__ ln_a_b, const float* __restrict__ lnzw,
                             const float* __restrict__ lnzb, const float* __restrict__ w_z,
                             const float* __restrict__ wq, const float* __restrict__ wk,
                             const float* __restrict__ wv, const float* __restrict__ wg,
                             const float* __restrict__ wo,
                             unsigned short* __restrict__ a_lnB, unsigned short* __restrict__ wBall,
                             unsigned short* __restrict__ wwB, float* __restrict__ TU){
  int bid = blockIdx.x, tid = threadIdx.x;
  if (bid < 180){
    __shared__ float t[64][65];
    int mat = bid/36, tt = bid - mat*36;
    int c0 = (tt % 6)*64, k0 = (tt / 6)*64;
    const float* src = mat == 0 ? wq : mat == 1 ? wk : mat == 2 ? wv : mat == 3 ? wg : wo;
    int r = tid >> 4, c4 = (tid & 15)*4;
    #pragma unroll
    for (int rr = 0; rr < 4; ++rr){
      float4 v = *(const float4*)(src + (size_t)(k0 + r + rr*16)*384 + c0 + c4);
      t[r + rr*16][c4+0] = v.x; t[r + rr*16][c4+1] = v.y;
      t[r + rr*16][c4+2] = v.z; t[r + rr*16][c4+3] = v.w;
    }
    __syncthreads();
    float scale = (mat == 0) ? 0.20412414523193154f : 1.f;
    int cc = tid >> 2, kp = (tid & 3)*16;
    unsigned ow[8];
    #pragma unroll
    for (int j = 0; j < 8; ++j)
      ow[j] = pk_bf(t[kp + 2*j][cc]*scale, t[kp + 2*j + 1][cc]*scale);
    unsigned short* dst = wBall + ((size_t)(mat*384 + c0 + cc)*384 + k0 + kp);
    *(uint4*)dst       = make_uint4(ow[0], ow[1], ow[2], ow[3]);
    *(uint4*)(dst + 8) = make_uint4(ow[4], ow[5], ow[6], ow[7]);
  } else if (bid < 436){
    int r = (bid - 180)*4 + (tid >> 6), l = tid & 63;
    const float* ap = a + (size_t)r*384;
    float x[6]; float s = 0.f, sq = 0.f;
    #pragma unroll
    for (int i = 0; i < 6; ++i){ x[i] = ap[i*64 + l]; s += x[i]; sq += x[i]*x[i]; }
    #pragma unroll
    for (int off = 32; off; off >>= 1){ s += __shfl_xor(s, off); sq += __shfl_xor(sq, off); }
    float mu = s*(1.f/384.f);
    float var = sq*(1.f/384.f) - mu*mu;
    float rs = rsqrtf(var + 1e-5f);
    #pragma unroll
    for (int i = 0; i < 6; ++i){ int c = i*64 + l; a_lnB[(size_t)r*384 + c] = f2bf((x[i]-mu)*rs*ln_a_w[c] + ln_a_b[c]); }
  } else {
    if (tid < 128){
      float lw = lnzw[tid];
      #pragma unroll
      for (int h = 0; h < 16; ++h) wwB[tid*16 + h] = f2bf(lw * w_z[tid*16 + h]);
    }
    if (tid < 16){
      float T = 0.f, U = 0.f;
      for (int c = 0; c < 128; ++c){ T += lnzw[c]*w_z[c*16 + tid]; U += lnzb[c]*w_z[c*16 + tid]; }
      TU[tid] = T; TU[16 + tid] = U;
    }
  }
}

// ---------------- fused QKVG: [1024x384]bf16 @ [384x1536]bf16 via MFMA ----------------
__global__ __launch_bounds__(256) void qkvg_kernel(const unsigned short* __restrict__ AB,
                                                   const unsigned short* __restrict__ wBt,
                                                   const float* __restrict__ bg,
                                                   float* __restrict__ qT, float* __restrict__ kT,
                                                   float* __restrict__ vT, float* __restrict__ g){
  __shared__ short Al[64*8*8];
  __shared__ short Bl[64*8*8];
  int tid = threadIdx.x;
  int wave = tid >> 6, lane = tid & 63, l15 = lane & 15, sub = lane >> 4;
  int n0 = blockIdx.x*64, m0 = blockIdx.y*64;
  f32x4 acc[4];
  #pragma unroll
  for (int c = 0; c < 4; ++c) acc[c] = (f32x4){0.f,0.f,0.f,0.f};
  const s16x8* Ag = (const s16x8*)AB;
  const s16x8* Bg = (const s16x8*)wBt;
  s16x8* Al8 = (s16x8*)Al; s16x8* Bl8 = (s16x8*)Bl;
  for (int ks = 0; ks < 6; ++ks){
    int k0u = ks*8;
    #pragma unroll
    for (int j = 0; j < 2; ++j){
      int idx = tid*2 + j;
      int row = idx >> 3, u = idx & 7;
      Al8[row*8 + (u ^ (row & 7))] = Ag[(size_t)(m0 + row)*48 + k0u + u];
      Bl8[row*8 + (u ^ (row & 7))] = Bg[(size_t)(n0 + row)*48 + k0u + u];
    }
    __syncthreads();
    #pragma unroll
    for (int kk = 0; kk < 2; ++kk){
      int arow = wave*16 + l15;
      s16x8 af = Al8[arow*8 + ((kk*4 + sub) ^ (arow & 7))];
      #pragma unroll
      for (int c = 0; c < 4; ++c){
        int brow = c*16 + l15;
        s16x8 bf = Bl8[brow*8 + ((kk*4 + sub) ^ (brow & 7))];
        acc[c] = __builtin_amdgcn_mfma_f32_16x16x32_bf16(af, bf, acc[c], 0, 0, 0);
      }
    }
    __syncthreads();
  }
  int which = blockIdx.x / 6;
  int cb = n0 - which*384;
  #pragma unroll
  for (int c = 0; c < 4; ++c){
    int col = cb + c*16 + l15;
    #pragma unroll
    for (int r = 0; r < 4; ++r){
      int row = m0 + wave*16 + sub*4 + r;
      float v = acc[c][r];
      if (which == 3){
        float t = v + bg[col];
        g[(size_t)row*384 + col] = 1.f/(1.f + __expf(-t));
      } else {
        int h = col/24, d = col - h*24;
        float* dst = which == 0 ? qT : which == 1 ? kT : vT;
        dst[((size_t)(h << 10) + row)*24 + d] = v;
      }
    }
  }
}

// ---------------- z bias v3: LDS-free A-fragments direct from global; mask folded; tiled pb ----------------
// pbT layout: [h][qb 16][kkb 32][q 64][kk 32]
__global__ __launch_bounds__(256) void zbias_kernel(const float* __restrict__ z, const unsigned short* __restrict__ wwB,
                                                    const float* __restrict__ TU, const float* __restrict__ mask,
                                                    unsigned short* __restrict__ pbT){
  __shared__ float sums[64];
  __shared__ float sqs[64];
  __shared__ float accT[64][17];
  int tid = threadIdx.x;
  int wave = tid >> 6, lane = tid & 63;
  int h = lane & 15, sub = lane >> 4;
  s16x8 bfr[4];
  #pragma unroll
  for (int kc = 0; kc < 4; ++kc)
    #pragma unroll
    for (int j = 0; j < 8; ++j) bfr[kc][j] = (short)wwB[(kc*32 + sub*8 + j)*16 + h];
  s16x8 ones1;                         // B col0 = 1.0 -> D[:,0] = row sums
  #pragma unroll
  for (int j = 0; j < 8; ++j) ones1[j] = (h == 0) ? (short)0x3F80 : (short)0;
  int eh = tid >> 4, epl0 = (tid & 15)*4;
  float Te = TU[eh], Ue = TU[16 + eh];
  int row = wave*16 + h;
  for (int rep = 0; rep < REP_ZB; ++rep){
  for (int it = 0; it < 4; ++it){
    int tile = blockIdx.x + it*4096;
    size_t pairBase = (size_t)tile*64;
    const float* zrow = z + (pairBase + row)*128;
    f32x4 acc  = {0.f, 0.f, 0.f, 0.f};
    f32x4 accS = {0.f, 0.f, 0.f, 0.f};
    f32x4 accG = {0.f, 0.f, 0.f, 0.f};
    #pragma unroll
    for (int kc = 0; kc < 4; ++kc){
      f32x4 v0 = *(const f32x4*)(zrow + kc*32 + sub*8);
      f32x4 v1 = *(const f32x4*)(zrow + kc*32 + sub*8 + 4);
      union { unsigned u[4]; s16x8 s; } cv;
      cv.u[0] = pk_bf(v0.x, v0.y); cv.u[1] = pk_bf(v0.z, v0.w);
      cv.u[2] = pk_bf(v1.x, v1.y); cv.u[3] = pk_bf(v1.z, v1.w);
      s16x8 af = cv.s;
      acc  = __builtin_amdgcn_mfma_f32_16x16x32_bf16(af, bfr[kc], acc, 0, 0, 0);
      accS = __builtin_amdgcn_mfma_f32_16x16x32_bf16(af, ones1, accS, 0, 0, 0);
      accG = __builtin_amdgcn_mfma_f32_16x16x32_bf16(af, af, accG, 0, 0, 0);
    }
    #pragma unroll
    for (int r = 0; r < 4; ++r) accT[wave*16 + sub*4 + r][h] = acc[r];
    if (h == 0){
      #pragma unroll
      for (int r = 0; r < 4; ++r) sums[wave*16 + sub*4 + r] = accS[r];
    }
    if (sub == (h >> 2)){
      int r = h & 3;
      float vq = r == 0 ? accG[0] : r == 1 ? accG[1] : r == 2 ? accG[2] : accG[3];
      sqs[wave*16 + h] = vq;
    }
    __syncthreads();
    float mus[4], rss[4];
    #pragma unroll
    for (int rr = 0; rr < 4; ++rr){
      float mu = sums[epl0+rr]*(1.f/128.f);
      float var = sqs[epl0+rr]*(1.f/128.f) - mu*mu;
      mus[rr] = mu; rss[rr] = rsqrtf(var + 1e-5f);
    }
    size_t p0 = pairBase + epl0;
    int q = (int)(p0 >> 10), k0 = (int)(p0 & 1023);
    float4 mk = *(const float4*)(mask + k0);
    ushort4 ov;
    ov.x = f2bf(rss[0]*(accT[epl0+0][eh] - mus[0]*Te) + Ue + 1e9f*(mk.x - 1.f));
    ov.y = f2bf(rss[1]*(accT[epl0+1][eh] - mus[1]*Te) + Ue + 1e9f*(mk.y - 1.f));
    ov.z = f2bf(rss[2]*(accT[epl0+2][eh] - mus[2]*Te) + Ue + 1e9f*(mk.z - 1.f));
    ov.w = f2bf(rss[3]*(accT[epl0+3][eh] - mus[3]*Te) + Ue + 1e9f*(mk.w - 1.f));
    size_t off = ((size_t)((eh*16 + (q >> 6))*32 + (k0 >> 5)))*2048 + (size_t)(q & 63)*32 + (k0 & 31);
    *(ushort4*)(pbT + off) = ov;
    __syncthreads();
  }
  }
}

// ---------------- attn v5: direct uniform global K/V (L2-resident, broadcast), pb in registers ----------------
// grid (16 qb, 16 h), 512 threads = 8 waves; wave w owns kk [w*128, w*128+128), 4 chunks of 32.
__global__ __launch_bounds__(512) void attn_kernel(const float* __restrict__ qT, const float* __restrict__ kT,
                                                   const float* __restrict__ vT, const unsigned short* __restrict__ pbT,
                                                   const float* __restrict__ g, unsigned short* __restrict__ ogB){
  __shared__ float lds[13824];     // combine area: 8*64*27 floats (55.3 KB)
  int wave = threadIdx.x >> 6, lane = threadIdx.x & 63;
  int qb = blockIdx.x, h = blockIdx.y;
  int q = qb*64 + lane;
  const float4* qp = (const float4*)(qT + ((size_t)(h << 10) + q)*24);
  float qv[24];
  #pragma unroll
  for (int i = 0; i < 6; ++i){ float4 t = qp[i]; qv[4*i] = t.x; qv[4*i+1] = t.y; qv[4*i+2] = t.z; qv[4*i+3] = t.w; }
  int kkw = wave*128;
  const unsigned short* pbW = pbT + ((size_t)((h*16 + qb)*32 + wave*4))*2048 + (size_t)lane*32;
  const float* kBase = kT + ((size_t)(h << 10))*24;
  const float* vBase = vT + ((size_t)(h << 10))*24;
  for (int rep = 0; rep < REP_ATTN; ++rep){
    float m = -1e30f, lsum = 0.f, ov[24];
    #pragma unroll
    for (int i = 0; i < 24; ++i) ov[i] = 0.f;
    for (int c = 0; c < 4; ++c){
      uint4 prC0 = *(const uint4*)(pbW + c*2048 + 0);
      uint4 prC1 = *(const uint4*)(pbW + c*2048 + 8);
      uint4 prC2 = *(const uint4*)(pbW + c*2048 + 16);
      uint4 prC3 = *(const uint4*)(pbW + c*2048 + 24);
      int kkc = kkw + c*32;
      #pragma unroll
      for (int grp = 0; grp < 8; ++grp){
        uint2 pu;
        if (grp == 0) pu = make_uint2(prC0.x, prC0.y);
        else if (grp == 1) pu = make_uint2(prC0.z, prC0.w);
        else if (grp == 2) pu = make_uint2(prC1.x, prC1.y);
        else if (grp == 3) pu = make_uint2(prC1.z, prC1.w);
        else if (grp == 4) pu = make_uint2(prC2.x, prC2.y);
        else if (grp == 5) pu = make_uint2(prC2.z, prC2.w);
        else if (grp == 6) pu = make_uint2(prC3.x, prC3.y);
        else pu = make_uint2(prC3.z, prC3.w);
        union { uint2 u; s16x4 s; } pc; pc.u = pu;
        s16x4 pbv = pc.s;
        const float4* kp = (const float4*)(kBase + (size_t)(kkc + grp*4)*24);
        const float4* vp = (const float4*)(vBase + (size_t)(kkc + grp*4)*24);
        float lg[4];
        #pragma unroll
        for (int j = 0; j < 4; ++j){
          float d0 = 0.f, d1 = 0.f, d2 = 0.f, d3 = 0.f;
          #pragma unroll
          for (int i = 0; i < 6; ++i){
            float4 kf = kp[j*6 + i];
            d0 += qv[4*i]*kf.x; d1 += qv[4*i+1]*kf.y; d2 += qv[4*i+2]*kf.z; d3 += qv[4*i+3]*kf.w;
          }
          lg[j] = (d0 + d1) + (d2 + d3) + bf2f((unsigned short)pbv[j]);
        }
        float gm = fmaxf(fmaxf(lg[0], lg[1]), fmaxf(lg[2], lg[3]));
        if (gm > m){
          float corr = __expf(m - gm);
          lsum *= corr;
          #pragma unroll
          for (int i = 0; i < 24; ++i) ov[i] *= corr;
          m = gm;
        }
        #pragma unroll
        for (int j = 0; j < 4; ++j){
          float p = __expf(lg[j] - m);
          lsum += p;
          #pragma unroll
          for (int i = 0; i < 6; ++i){
            float4 vf = vp[j*6 + i];
            ov[4*i]   += p*vf.x;
            ov[4*i+1] += p*vf.y;
            ov[4*i+2] += p*vf.z;
            ov[4*i+3] += p*vf.w;
          }
        }
      }
    }
    // ---- combine across 8 waves ----
    __syncthreads();
    {
      float* cw = lds + ((size_t)wave*64 + lane)*27;
      cw[0] = m; cw[1] = lsum;
      #pragma unroll
      for (int i = 0; i < 24; ++i) cw[2+i] = ov[i];
    }
    __syncthreads();
    #pragma unroll
    for (int s2 = 4; s2 >= 1; s2 >>= 1){
      if (wave < s2){
        float* c1 = lds + ((size_t)wave*64 + lane)*27;
        float* c2 = lds + ((size_t)(wave + s2)*64 + lane)*27;
        float m1 = c1[0], l1 = c1[1], m2 = c2[0], l2 = c2[1];
        float nm = fmaxf(m1, m2);
        float f1 = __expf(m1 - nm), f2 = __expf(m2 - nm);
        c1[0] = nm; c1[1] = l1*f1 + l2*f2;
        #pragma unroll
        for (int i = 0; i < 24; ++i) c1[2+i] = c1[2+i]*f1 + c2[2+i]*f2;
      }
      __syncthreads();
    }
    if (wave == 0){
      float* c0 = lds + (size_t)lane*27;
      float inv = 1.f/c0[1];
      size_t base = (size_t)q*384 + h*24;
      unsigned ow[12];
      #pragma unroll
      for (int i2 = 0; i2 < 6; ++i2){
        float4 gv = *(const float4*)(g + base + i2*4);
        ow[2*i2]   = pk_bf(gv.x*c0[2 + 4*i2]*inv, gv.y*c0[3 + 4*i2]*inv);
        ow[2*i2+1] = pk_bf(gv.z*c0[4 + 4*i2]*inv, gv.w*c0[5 + 4*i2]*inv);
      }
      uint4* dst = (uint4*)(ogB + base);
      dst[0] = make_uint4(ow[0], ow[1], ow[2],  ow[3]);
      dst[1] = make_uint4(ow[4], ow[5], ow[6],  ow[7]);
      dst[2] = make_uint4(ow[8], ow[9], ow[10], ow[11]);
    }
    __syncthreads();
  }
}

// ---------------- final projection: ogB[1024x384]bf16 @ wo^T bf16 via MFMA, + bo ----------------
__global__ __launch_bounds__(256) void gemm_out(const unsigned short* __restrict__ AB,
                                                const unsigned short* __restrict__ wBo,
                                                const float* __restrict__ bo, float* __restrict__ dst){
  __shared__ short Al[64*8*8];
  __shared__ short Bl[64*8*8];
  int tid = threadIdx.x;
  int wave = tid >> 6, lane = tid & 63, l15 = lane & 15, sub = lane >> 4;
  int n0 = blockIdx.x*64, m0 = blockIdx.y*64;
  f32x4 acc[4];
  #pragma unroll
  for (int c = 0; c < 4; ++c) acc[c] = (f32x4){0.f,0.f,0.f,0.f};
  const s16x8* Ag = (const s16x8*)AB;
  const s16x8* Bg = (const s16x8*)wBo;
  s16x8* Al8 = (s16x8*)Al; s16x8* Bl8 = (s16x8*)Bl;
  for (int ks = 0; ks < 6; ++ks){
    int k0u = ks*8;
    #pragma unroll
    for (int j = 0; j < 2; ++j){
      int idx = tid*2 + j;
      int row = idx >> 3, u = idx & 7;
      Al8[row*8 + (u ^ (row & 7))] = Ag[(size_t)(m0 + row)*48 + k0u + u];
      Bl8[row*8 + (u ^ (row & 7))] = Bg[(size_t)(n0 + row)*48 + k0u + u];
    }
    __syncthreads();
    #pragma unroll
    for (int kk = 0; kk < 2; ++kk){
      int arow = wave*16 + l15;
      s16x8 af = Al8[arow*8 + ((kk*4 + sub) ^ (arow & 7))];
      #pragma unroll
      for (int c = 0; c < 4; ++c){
        int brow = c*16 + l15;
        s16x8 bf = Bl8[brow*8 + ((kk*4 + sub) ^ (brow & 7))];
        acc[c] = __builtin_amdgcn_mfma_f32_16x16x32_bf16(af, bf, acc[c], 0, 0, 0);
      }
    }
    __syncthreads();
  }
  #pragma unroll
  for (int c = 0; c < 4; ++c){
    int col = n0 + c*16 + l15;
    float b = bo[col];
    #pragma unroll
    for (int r = 0; r < 4; ++r){
      int row = m0 + wave*16 + sub*4 + r;
      dst[(size_t)row*384 + col] = acc[c][r] + b;
    }
  }
}

extern "C" void kernel_launch(void* const* d_in, const int* in_sizes, int n_in,
                              void* d_out, int out_size, void* d_ws, size_t ws_size,
                              hipStream_t stream){
  const float* a      = (const float*)d_in[0];
  const float* z      = (const float*)d_in[1];
  const float* mask   = (const float*)d_in[2];
  const float* ln_a_w = (const float*)d_in[3];
  const float* ln_a_b = (const float*)d_in[4];
  const float* ln_z_w = (const float*)d_in[5];
  const float* ln_z_b = (const float*)d_in[6];
  const float* w_z    = (const float*)d_in[7];
  const float* wq     = (const float*)d_in[8];
  const float* wk     = (const float*)d_in[9];
  const float* wv     = (const float*)d_in[10];
  const float* wg     = (const float*)d_in[11];
  const float* bg     = (const float*)d_in[12];
  const float* wo     = (const float*)d_in[13];
  const float* bo     = (const float*)d_in[14];

  char* ws = (char*)d_ws;
  unsigned short* a_lnB = (unsigned short*)(ws + ((size_t)0u));
  unsigned short* wBall = (unsigned short*)(ws + ((size_t)1u << 20));
  float* qT   = (float*)(ws + ((size_t)4u << 20));
  float* kT   = (float*)(ws + ((size_t)6u << 20));
  float* vT   = (float*)(ws + ((size_t)8u << 20));
  float* g    = (float*)(ws + ((size_t)10u << 20));
  unsigned short* ogB = (unsigned short*)(ws + ((size_t)12u << 20));
  unsigned short* wwB = (unsigned short*)(ws + ((size_t)14u << 20));
  float* TU   = (float*)(ws + ((size_t)14u << 20) + 8192);
  unsigned short* pbT = (unsigned short*)(ws + ((size_t)24u << 20));

  hipLaunchKernelGGL(prep_kernel, dim3(437), dim3(256), 0, stream, a, ln_a_w, ln_a_b,
                     ln_z_w, ln_z_b, w_z, wq, wk, wv, wg, wo, a_lnB, wBall, wwB, TU);
  hipLaunchKernelGGL(qkvg_kernel, dim3(24,16), dim3(256), 0, stream, a_lnB, wBall, bg, qT, kT, vT, g);
  hipLaunchKernelGGL(zbias_kernel, dim3(4096), dim3(256), 0, stream, z, wwB, TU, mask, pbT);
  hipLaunchKernelGGL(attn_kernel, dim3(16,16), dim3(512), 0, stream, qT, kT, vT, pbT, g, ogB);
  hipLaunchKernelGGL(gemm_out, dim3(6,16), dim3(256), 0, stream, ogB, wBall + (size_t)4*384*384, bo, (float*)d_out);
}

// Round 10
// 259.563 us; speedup vs baseline: 7.8008x; 7.8008x over previous
//
#include <hip/hip_runtime.h>
#include <hip/hip_bf16.h>

typedef float f32x4 __attribute__((ext_vector_type(4)));
typedef short s16x8 __attribute__((ext_vector_type(8)));
typedef short s16x4 __attribute__((ext_vector_type(4)));

__device__ __forceinline__ unsigned short f2bf(float x){
  unsigned u = __float_as_uint(x);
  u += 0x7fffu + ((u >> 16) & 1u);
  return (unsigned short)(u >> 16);
}
__device__ __forceinline__ float bf2f(unsigned short h){
  return __uint_as_float(((unsigned)h) << 16);
}
__device__ __forceinline__ unsigned pk_bf(float a, float b){
  __hip_bfloat162 t = __float22bfloat162_rn(make_float2(a, b));
  return *reinterpret_cast<unsigned*>(&t);
}

// ---------------- prep: weight transpose->bf16 (0..179), ln_a (180..435), setup (436) ----------------
__global__ __launch_bounds__(256) void prep_kernel(const float* __restrict__ a, const float* __restrict__ ln_a_w,
                             const float* __restrict__ ln_a_b, const float* __restrict__ lnzw,
                             const float* __restrict__ lnzb, const float* __restrict__ w_z,
                             const float* __restrict__ wq, const float* __restrict__ wk,
                             const float* __restrict__ wv, const float* __restrict__ wg,
                             const float* __restrict__ wo,
                             unsigned short* __restrict__ a_lnB, unsigned short* __restrict__ wBall,
                             unsigned short* __restrict__ wwB, float* __restrict__ TU){
  int bid = blockIdx.x, tid = threadIdx.x;
  if (bid < 180){
    __shared__ float t[64][65];
    int mat = bid/36, tt = bid - mat*36;
    int c0 = (tt % 6)*64, k0 = (tt / 6)*64;
    const float* src = mat == 0 ? wq : mat == 1 ? wk : mat == 2 ? wv : mat == 3 ? wg : wo;
    int r = tid >> 4, c4 = (tid & 15)*4;
    #pragma unroll
    for (int rr = 0; rr < 4; ++rr){
      float4 v = *(const float4*)(src + (size_t)(k0 + r + rr*16)*384 + c0 + c4);
      t[r + rr*16][c4+0] = v.x; t[r + rr*16][c4+1] = v.y;
      t[r + rr*16][c4+2] = v.z; t[r + rr*16][c4+3] = v.w;
    }
    __syncthreads();
    float scale = (mat == 0) ? 0.20412414523193154f : 1.f;
    int cc = tid >> 2, kp = (tid & 3)*16;
    unsigned ow[8];
    #pragma unroll
    for (int j = 0; j < 8; ++j)
      ow[j] = pk_bf(t[kp + 2*j][cc]*scale, t[kp + 2*j + 1][cc]*scale);
    unsigned short* dst = wBall + ((size_t)(mat*384 + c0 + cc)*384 + k0 + kp);
    *(uint4*)dst       = make_uint4(ow[0], ow[1], ow[2], ow[3]);
    *(uint4*)(dst + 8) = make_uint4(ow[4], ow[5], ow[6], ow[7]);
  } else if (bid < 436){
    int r = (bid - 180)*4 + (tid >> 6), l = tid & 63;
    const float* ap = a + (size_t)r*384;
    float x[6]; float s = 0.f, sq = 0.f;
    #pragma unroll
    for (int i = 0; i < 6; ++i){ x[i] = ap[i*64 + l]; s += x[i]; sq += x[i]*x[i]; }
    #pragma unroll
    for (int off = 32; off; off >>= 1){ s += __shfl_xor(s, off); sq += __shfl_xor(sq, off); }
    float mu = s*(1.f/384.f);
    float var = sq*(1.f/384.f) - mu*mu;
    float rs = rsqrtf(var + 1e-5f);
    #pragma unroll
    for (int i = 0; i < 6; ++i){ int c = i*64 + l; a_lnB[(size_t)r*384 + c] = f2bf((x[i]-mu)*rs*ln_a_w[c] + ln_a_b[c]); }
  } else {
    if (tid < 128){
      float lw = lnzw[tid];
      #pragma unroll
      for (int h = 0; h < 16; ++h) wwB[tid*16 + h] = f2bf(lw * w_z[tid*16 + h]);
    }
    if (tid < 16){
      float T = 0.f, U = 0.f;
      for (int c = 0; c < 128; ++c){ T += lnzw[c]*w_z[c*16 + tid]; U += lnzb[c]*w_z[c*16 + tid]; }
      TU[tid] = T; TU[16 + tid] = U;
    }
  }
}

// ---------------- fused QKVG: [1024x384]bf16 @ [384x1536]bf16 via MFMA ----------------
__global__ __launch_bounds__(256) void qkvg_kernel(const unsigned short* __restrict__ AB,
                                                   const unsigned short* __restrict__ wBt,
                                                   const float* __restrict__ bg,
                                                   float* __restrict__ qT, float* __restrict__ kT,
                                                   float* __restrict__ vT, float* __restrict__ g){
  __shared__ short Al[64*8*8];
  __shared__ short Bl[64*8*8];
  int tid = threadIdx.x;
  int wave = tid >> 6, lane = tid & 63, l15 = lane & 15, sub = lane >> 4;
  int n0 = blockIdx.x*64, m0 = blockIdx.y*64;
  f32x4 acc[4];
  #pragma unroll
  for (int c = 0; c < 4; ++c) acc[c] = (f32x4){0.f,0.f,0.f,0.f};
  const s16x8* Ag = (const s16x8*)AB;
  const s16x8* Bg = (const s16x8*)wBt;
  s16x8* Al8 = (s16x8*)Al; s16x8* Bl8 = (s16x8*)Bl;
  for (int ks = 0; ks < 6; ++ks){
    int k0u = ks*8;
    #pragma unroll
    for (int j = 0; j < 2; ++j){
      int idx = tid*2 + j;
      int row = idx >> 3, u = idx & 7;
      Al8[row*8 + (u ^ (row & 7))] = Ag[(size_t)(m0 + row)*48 + k0u + u];
      Bl8[row*8 + (u ^ (row & 7))] = Bg[(size_t)(n0 + row)*48 + k0u + u];
    }
    __syncthreads();
    #pragma unroll
    for (int kk = 0; kk < 2; ++kk){
      int arow = wave*16 + l15;
      s16x8 af = Al8[arow*8 + ((kk*4 + sub) ^ (arow & 7))];
      #pragma unroll
      for (int c = 0; c < 4; ++c){
        int brow = c*16 + l15;
        s16x8 bf = Bl8[brow*8 + ((kk*4 + sub) ^ (brow & 7))];
        acc[c] = __builtin_amdgcn_mfma_f32_16x16x32_bf16(af, bf, acc[c], 0, 0, 0);
      }
    }
    __syncthreads();
  }
  int which = blockIdx.x / 6;
  int cb = n0 - which*384;
  #pragma unroll
  for (int c = 0; c < 4; ++c){
    int col = cb + c*16 + l15;
    #pragma unroll
    for (int r = 0; r < 4; ++r){
      int row = m0 + wave*16 + sub*4 + r;
      float v = acc[c][r];
      if (which == 3){
        float t = v + bg[col];
        g[(size_t)row*384 + col] = 1.f/(1.f + __expf(-t));
      } else {
        int h = col/24, d = col - h*24;
        float* dst = which == 0 ? qT : which == 1 ? kT : vT;
        dst[((size_t)(h << 10) + row)*24 + d] = v;
      }
    }
  }
}

// ---------------- z bias v3: LDS-free A-fragments direct from global; mask folded; tiled pb ----------------
// pbT layout: [h][qb 16][kkb 32][q 64][kk 32]
__global__ __launch_bounds__(256) void zbias_kernel(const float* __restrict__ z, const unsigned short* __restrict__ wwB,
                                                    const float* __restrict__ TU, const float* __restrict__ mask,
                                                    unsigned short* __restrict__ pbT){
  __shared__ float sums[64];
  __shared__ float sqs[64];
  __shared__ float accT[64][17];
  int tid = threadIdx.x;
  int wave = tid >> 6, lane = tid & 63;
  int h = lane & 15, sub = lane >> 4;
  s16x8 bfr[4];
  #pragma unroll
  for (int kc = 0; kc < 4; ++kc)
    #pragma unroll
    for (int j = 0; j < 8; ++j) bfr[kc][j] = (short)wwB[(kc*32 + sub*8 + j)*16 + h];
  s16x8 ones1;                         // B col0 = 1.0 -> D[:,0] = row sums
  #pragma unroll
  for (int j = 0; j < 8; ++j) ones1[j] = (h == 0) ? (short)0x3F80 : (short)0;
  int eh = tid >> 4, epl0 = (tid & 15)*4;
  float Te = TU[eh], Ue = TU[16 + eh];
  int row = wave*16 + h;
  for (int it = 0; it < 4; ++it){
    int tile = blockIdx.x + it*4096;
    size_t pairBase = (size_t)tile*64;
    const float* zrow = z + (pairBase + row)*128;
    f32x4 acc  = {0.f, 0.f, 0.f, 0.f};
    f32x4 accS = {0.f, 0.f, 0.f, 0.f};
    f32x4 accG = {0.f, 0.f, 0.f, 0.f};
    #pragma unroll
    for (int kc = 0; kc < 4; ++kc){
      f32x4 v0 = *(const f32x4*)(zrow + kc*32 + sub*8);
      f32x4 v1 = *(const f32x4*)(zrow + kc*32 + sub*8 + 4);
      union { unsigned u[4]; s16x8 s; } cv;
      cv.u[0] = pk_bf(v0.x, v0.y); cv.u[1] = pk_bf(v0.z, v0.w);
      cv.u[2] = pk_bf(v1.x, v1.y); cv.u[3] = pk_bf(v1.z, v1.w);
      s16x8 af = cv.s;
      acc  = __builtin_amdgcn_mfma_f32_16x16x32_bf16(af, bfr[kc], acc, 0, 0, 0);
      accS = __builtin_amdgcn_mfma_f32_16x16x32_bf16(af, ones1, accS, 0, 0, 0);
      accG = __builtin_amdgcn_mfma_f32_16x16x32_bf16(af, af, accG, 0, 0, 0);
    }
    #pragma unroll
    for (int r = 0; r < 4; ++r) accT[wave*16 + sub*4 + r][h] = acc[r];
    if (h == 0){
      #pragma unroll
      for (int r = 0; r < 4; ++r) sums[wave*16 + sub*4 + r] = accS[r];
    }
    if (sub == (h >> 2)){
      int r = h & 3;
      float vq = r == 0 ? accG[0] : r == 1 ? accG[1] : r == 2 ? accG[2] : accG[3];
      sqs[wave*16 + h] = vq;
    }
    __syncthreads();
    float mus[4], rss[4];
    #pragma unroll
    for (int rr = 0; rr < 4; ++rr){
      float mu = sums[epl0+rr]*(1.f/128.f);
      float var = sqs[epl0+rr]*(1.f/128.f) - mu*mu;
      mus[rr] = mu; rss[rr] = rsqrtf(var + 1e-5f);
    }
    size_t p0 = pairBase + epl0;
    int q = (int)(p0 >> 10), k0 = (int)(p0 & 1023);
    float4 mk = *(const float4*)(mask + k0);
    ushort4 ov;
    ov.x = f2bf(rss[0]*(accT[epl0+0][eh] - mus[0]*Te) + Ue + 1e9f*(mk.x - 1.f));
    ov.y = f2bf(rss[1]*(accT[epl0+1][eh] - mus[1]*Te) + Ue + 1e9f*(mk.y - 1.f));
    ov.z = f2bf(rss[2]*(accT[epl0+2][eh] - mus[2]*Te) + Ue + 1e9f*(mk.z - 1.f));
    ov.w = f2bf(rss[3]*(accT[epl0+3][eh] - mus[3]*Te) + Ue + 1e9f*(mk.w - 1.f));
    size_t off = ((size_t)((eh*16 + (q >> 6))*32 + (k0 >> 5)))*2048 + (size_t)(q & 63)*32 + (k0 & 31);
    *(ushort4*)(pbT + off) = ov;
    __syncthreads();
  }
}

// ---------------- attn v6: kk-split grid (4,16,16), 4 waves/block, pb in regs, partials + merge ----------------
__global__ __launch_bounds__(256) void attn_kernel(const float* __restrict__ qT, const float* __restrict__ kT,
                                                   const float* __restrict__ vT, const unsigned short* __restrict__ pbT,
                                                   float* __restrict__ part){
  __shared__ float lds[4*64*27];   // 27.6 KB
  int s = blockIdx.x, qb = blockIdx.y, h = blockIdx.z;
  int wave = threadIdx.x >> 6, lane = threadIdx.x & 63;
  int q = qb*64 + lane;
  const float4* qp = (const float4*)(qT + ((size_t)(h << 10) + q)*24);
  float qv[24];
  #pragma unroll
  for (int i = 0; i < 6; ++i){ float4 t = qp[i]; qv[4*i] = t.x; qv[4*i+1] = t.y; qv[4*i+2] = t.z; qv[4*i+3] = t.w; }
  int kk0 = s*256 + wave*64;
  const unsigned short* pbW = pbT + ((size_t)((h*16 + qb)*32 + s*8 + wave*2))*2048 + (size_t)lane*32;
  uint4 pA0 = *(const uint4*)(pbW + 0),    pA1 = *(const uint4*)(pbW + 8);
  uint4 pA2 = *(const uint4*)(pbW + 16),   pA3 = *(const uint4*)(pbW + 24);
  uint4 pB0 = *(const uint4*)(pbW + 2048), pB1 = *(const uint4*)(pbW + 2056);
  uint4 pB2 = *(const uint4*)(pbW + 2064), pB3 = *(const uint4*)(pbW + 2072);
  const float* kBase = kT + ((size_t)(h << 10))*24;
  const float* vBase = vT + ((size_t)(h << 10))*24;
  float m = -1e30f, lsum = 0.f, ov[24];
  #pragma unroll
  for (int i = 0; i < 24; ++i) ov[i] = 0.f;
  auto CHUNK = [&](int kkc, uint4 c0, uint4 c1, uint4 c2, uint4 c3){
    #pragma unroll
    for (int grp = 0; grp < 8; ++grp){
      uint2 pu;
      if (grp == 0) pu = make_uint2(c0.x, c0.y);
      else if (grp == 1) pu = make_uint2(c0.z, c0.w);
      else if (grp == 2) pu = make_uint2(c1.x, c1.y);
      else if (grp == 3) pu = make_uint2(c1.z, c1.w);
      else if (grp == 4) pu = make_uint2(c2.x, c2.y);
      else if (grp == 5) pu = make_uint2(c2.z, c2.w);
      else if (grp == 6) pu = make_uint2(c3.x, c3.y);
      else pu = make_uint2(c3.z, c3.w);
      union { uint2 u; s16x4 s; } pc; pc.u = pu;
      s16x4 pbv = pc.s;
      const float4* kp = (const float4*)(kBase + (size_t)(kkc + grp*4)*24);
      const float4* vp = (const float4*)(vBase + (size_t)(kkc + grp*4)*24);
      float lg[4];
      #pragma unroll
      for (int j = 0; j < 4; ++j){
        float d0 = 0.f, d1 = 0.f, d2 = 0.f, d3 = 0.f;
        #pragma unroll
        for (int i = 0; i < 6; ++i){
          float4 kf = kp[j*6 + i];
          d0 += qv[4*i]*kf.x; d1 += qv[4*i+1]*kf.y; d2 += qv[4*i+2]*kf.z; d3 += qv[4*i+3]*kf.w;
        }
        lg[j] = (d0 + d1) + (d2 + d3) + bf2f((unsigned short)pbv[j]);
      }
      float gm = fmaxf(fmaxf(lg[0], lg[1]), fmaxf(lg[2], lg[3]));
      if (gm > m){
        float corr = __expf(m - gm);
        lsum *= corr;
        #pragma unroll
        for (int i = 0; i < 24; ++i) ov[i] *= corr;
        m = gm;
      }
      #pragma unroll
      for (int j = 0; j < 4; ++j){
        float p = __expf(lg[j] - m);
        lsum += p;
        #pragma unroll
        for (int i = 0; i < 6; ++i){
          float4 vf = vp[j*6 + i];
          ov[4*i]   += p*vf.x;
          ov[4*i+1] += p*vf.y;
          ov[4*i+2] += p*vf.z;
          ov[4*i+3] += p*vf.w;
        }
      }
    }
  };
  CHUNK(kk0,      pA0, pA1, pA2, pA3);
  CHUNK(kk0 + 32, pB0, pB1, pB2, pB3);
  // ---- combine 4 waves in LDS ----
  {
    float* cw = lds + ((size_t)wave*64 + lane)*27;
    cw[0] = m; cw[1] = lsum;
    #pragma unroll
    for (int i = 0; i < 24; ++i) cw[2+i] = ov[i];
  }
  __syncthreads();
  #pragma unroll
  for (int s2 = 2; s2 >= 1; s2 >>= 1){
    if (wave < s2){
      float* c1 = lds + ((size_t)wave*64 + lane)*27;
      float* c2 = lds + ((size_t)(wave + s2)*64 + lane)*27;
      float m1 = c1[0], l1 = c1[1], m2 = c2[0], l2 = c2[1];
      float nm = fmaxf(m1, m2);
      float f1 = __expf(m1 - nm), f2 = __expf(m2 - nm);
      c1[0] = nm; c1[1] = l1*f1 + l2*f2;
      #pragma unroll
      for (int i = 0; i < 24; ++i) c1[2+i] = c1[2+i]*f1 + c2[2+i]*f2;
    }
    __syncthreads();
  }
  if (wave == 0){
    float* c0 = lds + (size_t)lane*27;
    float* pw = part + ((size_t)((h*16 + qb)*4 + s)*64 + lane)*32;
    *(float2*)pw = make_float2(c0[0], c0[1]);
    #pragma unroll
    for (int i = 0; i < 6; ++i){
      float4 o4 = make_float4(c0[2+4*i], c0[3+4*i], c0[4+4*i], c0[5+4*i]);
      *(float4*)(pw + 4 + i*4) = o4;
    }
  }
}

// ---------------- merge 4 split-partials, apply gate, emit bf16 og ----------------
__global__ __launch_bounds__(64) void merge_kernel(const float* __restrict__ part, const float* __restrict__ g,
                                                   unsigned short* __restrict__ ogB){
  int gid = blockIdx.x*64 + threadIdx.x;
  int h = gid >> 10, q = gid & 1023;
  float M = -1e30f, L = 0.f, O[24];
  #pragma unroll
  for (int i = 0; i < 24; ++i) O[i] = 0.f;
  #pragma unroll
  for (int sp = 0; sp < 4; ++sp){
    const float* pr = part + ((size_t)((h*16 + (q >> 6))*4 + sp)*64 + (q & 63))*32;
    float2 ml = *(const float2*)pr;
    float nm = fmaxf(M, ml.x);
    float c1 = __expf(M - nm), c2 = __expf(ml.x - nm);
    L = L*c1 + ml.y*c2;
    #pragma unroll
    for (int i = 0; i < 6; ++i){
      float4 pv = *(const float4*)(pr + 4 + i*4);
      O[4*i]   = O[4*i]  *c1 + pv.x*c2;
      O[4*i+1] = O[4*i+1]*c1 + pv.y*c2;
      O[4*i+2] = O[4*i+2]*c1 + pv.z*c2;
      O[4*i+3] = O[4*i+3]*c1 + pv.w*c2;
    }
    M = nm;
  }
  float inv = 1.f/L;
  size_t base = (size_t)q*384 + h*24;
  unsigned ow[12];
  #pragma unroll
  for (int i = 0; i < 6; ++i){
    float4 gv = *(const float4*)(g + base + i*4);
    ow[2*i]   = pk_bf(gv.x*O[4*i]*inv,   gv.y*O[4*i+1]*inv);
    ow[2*i+1] = pk_bf(gv.z*O[4*i+2]*inv, gv.w*O[4*i+3]*inv);
  }
  uint4* dst = (uint4*)(ogB + base);
  dst[0] = make_uint4(ow[0], ow[1], ow[2],  ow[3]);
  dst[1] = make_uint4(ow[4], ow[5], ow[6],  ow[7]);
  dst[2] = make_uint4(ow[8], ow[9], ow[10], ow[11]);
}

// ---------------- final projection: ogB[1024x384]bf16 @ wo^T bf16 via MFMA, + bo ----------------
__global__ __launch_bounds__(256) void gemm_out(const unsigned short* __restrict__ AB,
                                                const unsigned short* __restrict__ wBo,
                                                const float* __restrict__ bo, float* __restrict__ dst){
  __shared__ short Al[64*8*8];
  __shared__ short Bl[64*8*8];
  int tid = threadIdx.x;
  int wave = tid >> 6, lane = tid & 63, l15 = lane & 15, sub = lane >> 4;
  int n0 = blockIdx.x*64, m0 = blockIdx.y*64;
  f32x4 acc[4];
  #pragma unroll
  for (int c = 0; c < 4; ++c) acc[c] = (f32x4){0.f,0.f,0.f,0.f};
  const s16x8* Ag = (const s16x8*)AB;
  const s16x8* Bg = (const s16x8*)wBo;
  s16x8* Al8 = (s16x8*)Al; s16x8* Bl8 = (s16x8*)Bl;
  for (int ks = 0; ks < 6; ++ks){
    int k0u = ks*8;
    #pragma unroll
    for (int j = 0; j < 2; ++j){
      int idx = tid*2 + j;
      int row = idx >> 3, u = idx & 7;
      Al8[row*8 + (u ^ (row & 7))] = Ag[(size_t)(m0 + row)*48 + k0u + u];
      Bl8[row*8 + (u ^ (row & 7))] = Bg[(size_t)(n0 + row)*48 + k0u + u];
    }
    __syncthreads();
    #pragma unroll
    for (int kk = 0; kk < 2; ++kk){
      int arow = wave*16 + l15;
      s16x8 af = Al8[arow*8 + ((kk*4 + sub) ^ (arow & 7))];
      #pragma unroll
      for (int c = 0; c < 4; ++c){
        int brow = c*16 + l15;
        s16x8 bf = Bl8[brow*8 + ((kk*4 + sub) ^ (brow & 7))];
        acc[c] = __builtin_amdgcn_mfma_f32_16x16x32_bf16(af, bf, acc[c], 0, 0, 0);
      }
    }
    __syncthreads();
  }
  #pragma unroll
  for (int c = 0; c < 4; ++c){
    int col = n0 + c*16 + l15;
    float b = bo[col];
    #pragma unroll
    for (int r = 0; r < 4; ++r){
      int row = m0 + wave*16 + sub*4 + r;
      dst[(size_t)row*384 + col] = acc[c][r] + b;
    }
  }
}

extern "C" void kernel_launch(void* const* d_in, const int* in_sizes, int n_in,
                              void* d_out, int out_size, void* d_ws, size_t ws_size,
                              hipStream_t stream){
  const float* a      = (const float*)d_in[0];
  const float* z      = (const float*)d_in[1];
  const float* mask   = (const float*)d_in[2];
  const float* ln_a_w = (const float*)d_in[3];
  const float* ln_a_b = (const float*)d_in[4];
  const float* ln_z_w = (const float*)d_in[5];
  const float* ln_z_b = (const float*)d_in[6];
  const float* w_z    = (const float*)d_in[7];
  const float* wq     = (const float*)d_in[8];
  const float* wk     = (const float*)d_in[9];
  const float* wv     = (const float*)d_in[10];
  const float* wg     = (const float*)d_in[11];
  const float* bg     = (const float*)d_in[12];
  const float* wo     = (const float*)d_in[13];
  const float* bo     = (const float*)d_in[14];

  char* ws = (char*)d_ws;
  unsigned short* a_lnB = (unsigned short*)(ws + ((size_t)0u));
  unsigned short* wBall = (unsigned short*)(ws + ((size_t)1u << 20));
  float* qT   = (float*)(ws + ((size_t)4u << 20));
  float* kT   = (float*)(ws + ((size_t)6u << 20));
  float* vT   = (float*)(ws + ((size_t)8u << 20));
  float* g    = (float*)(ws + ((size_t)10u << 20));
  unsigned short* ogB = (unsigned short*)(ws + ((size_t)12u << 20));
  unsigned short* wwB = (unsigned short*)(ws + ((size_t)14u << 20));
  float* TU   = (float*)(ws + ((size_t)14u << 20) + 8192);
  float* part = (float*)(ws + ((size_t)15u << 20));
  unsigned short* pbT = (unsigned short*)(ws + ((size_t)24u << 20));

  hipLaunchKernelGGL(prep_kernel, dim3(437), dim3(256), 0, stream, a, ln_a_w, ln_a_b,
                     ln_z_w, ln_z_b, w_z, wq, wk, wv, wg, wo, a_lnB, wBall, wwB, TU);
  hipLaunchKernelGGL(qkvg_kernel, dim3(24,16), dim3(256), 0, stream, a_lnB, wBall, bg, qT, kT, vT, g);
  hipLaunchKernelGGL(zbias_kernel, dim3(4096), dim3(256), 0, stream, z, wwB, TU, mask, pbT);
  hipLaunchKernelGGL(attn_kernel, dim3(4,16,16), dim3(256), 0, stream, qT, kT, vT, pbT, part);
  hipLaunchKernelGGL(merge_kernel, dim3(256), dim3(64), 0, stream, part, g, ogB);
  hipLaunchKernelGGL(gemm_out, dim3(6,16), dim3(256), 0, stream, ogB, wBall + (size_t)4*384*384, bo, (float*)d_out);
}

// Round 11
// 173.871 us; speedup vs baseline: 11.6455x; 1.4929x over previous
//
#include <hip/hip_runtime.h>
#include <hip/hip_bf16.h>

typedef float f32x4 __attribute__((ext_vector_type(4)));
typedef short s16x8 __attribute__((ext_vector_type(8)));

__device__ __forceinline__ unsigned short f2bf(float x){
  unsigned u = __float_as_uint(x);
  u += 0x7fffu + ((u >> 16) & 1u);
  return (unsigned short)(u >> 16);
}
__device__ __forceinline__ float bf2f(unsigned short h){
  return __uint_as_float(((unsigned)h) << 16);
}
__device__ __forceinline__ unsigned pk_bf(float a, float b){
  __hip_bfloat162 t = __float22bfloat162_rn(make_float2(a, b));
  return *reinterpret_cast<unsigned*>(&t);
}

// ---- prep: weight transpose->bf16 (0..179), ln_a (180..435), setup (436), zero-pads (437..628) ----
__global__ __launch_bounds__(256) void prep_kernel(const float* __restrict__ a, const float* __restrict__ ln_a_w,
                             const float* __restrict__ ln_a_b, const float* __restrict__ lnzw,
                             const float* __restrict__ lnzb, const float* __restrict__ w_z,
                             const float* __restrict__ wq, const float* __restrict__ wk,
                             const float* __restrict__ wv, const float* __restrict__ wg,
                             const float* __restrict__ wo,
                             unsigned short* __restrict__ a_lnB, unsigned short* __restrict__ wBall,
                             unsigned short* __restrict__ wwB, float* __restrict__ TU,
                             unsigned short* __restrict__ qTp, unsigned short* __restrict__ kTp,
                             unsigned short* __restrict__ vTt){
  int bid = blockIdx.x, tid = threadIdx.x;
  if (bid < 180){
    __shared__ float t[64][65];
    int mat = bid/36, tt = bid - mat*36;
    int c0 = (tt % 6)*64, k0 = (tt / 6)*64;
    const float* src = mat == 0 ? wq : mat == 1 ? wk : mat == 2 ? wv : mat == 3 ? wg : wo;
    int r = tid >> 4, c4 = (tid & 15)*4;
    #pragma unroll
    for (int rr = 0; rr < 4; ++rr){
      float4 v = *(const float4*)(src + (size_t)(k0 + r + rr*16)*384 + c0 + c4);
      t[r + rr*16][c4+0] = v.x; t[r + rr*16][c4+1] = v.y;
      t[r + rr*16][c4+2] = v.z; t[r + rr*16][c4+3] = v.w;
    }
    __syncthreads();
    float scale = (mat == 0) ? 0.20412414523193154f : 1.f;
    int cc = tid >> 2, kp = (tid & 3)*16;
    unsigned ow[8];
    #pragma unroll
    for (int j = 0; j < 8; ++j)
      ow[j] = pk_bf(t[kp + 2*j][cc]*scale, t[kp + 2*j + 1][cc]*scale);
    unsigned short* dst = wBall + ((size_t)(mat*384 + c0 + cc)*384 + k0 + kp);
    *(uint4*)dst       = make_uint4(ow[0], ow[1], ow[2], ow[3]);
    *(uint4*)(dst + 8) = make_uint4(ow[4], ow[5], ow[6], ow[7]);
  } else if (bid < 436){
    int r = (bid - 180)*4 + (tid >> 6), l = tid & 63;
    const float* ap = a + (size_t)r*384;
    float x[6]; float s = 0.f, sq = 0.f;
    #pragma unroll
    for (int i = 0; i < 6; ++i){ x[i] = ap[i*64 + l]; s += x[i]; sq += x[i]*x[i]; }
    #pragma unroll
    for (int off = 32; off; off >>= 1){ s += __shfl_xor(s, off); sq += __shfl_xor(sq, off); }
    float mu = s*(1.f/384.f);
    float var = sq*(1.f/384.f) - mu*mu;
    float rs = rsqrtf(var + 1e-5f);
    #pragma unroll
    for (int i = 0; i < 6; ++i){ int c = i*64 + l; a_lnB[(size_t)r*384 + c] = f2bf((x[i]-mu)*rs*ln_a_w[c] + ln_a_b[c]); }
  } else if (bid == 436){
    if (tid < 128){
      float lw = lnzw[tid];
      #pragma unroll
      for (int h = 0; h < 16; ++h) wwB[tid*16 + h] = f2bf(lw * w_z[tid*16 + h]);
    }
    if (tid < 16){
      float T = 0.f, U = 0.f;
      for (int c = 0; c < 128; ++c){ T += lnzw[c]*w_z[c*16 + tid]; U += lnzb[c]*w_z[c*16 + tid]; }
      TU[tid] = T; TU[16 + tid] = U;
    }
  } else {
    int t = (bid - 437)*256 + tid;       // 0..49151
    uint4 zv = make_uint4(0,0,0,0);
    if (t < 16384)      *(uint4*)(qTp + (size_t)t*32 + 24) = zv;
    else if (t < 32768) *(uint4*)(kTp + (size_t)(t - 16384)*32 + 24) = zv;
    else {
      int t2 = t - 32768;                 // 0..16383
      int h = t2 >> 10, w = t2 & 1023;
      *(uint4*)(vTt + ((size_t)h*32 + 24)*1024 + (size_t)w*8) = zv;
    }
  }
}

// ---- fused QKVG MFMA: emits qTp/kTp bf16 [h][1024][32], vTt bf16 [h][32][1024], g f32 ----
__global__ __launch_bounds__(256) void qkvg_kernel(const unsigned short* __restrict__ AB,
                                                   const unsigned short* __restrict__ wBt,
                                                   const float* __restrict__ bg,
                                                   unsigned short* __restrict__ qTp, unsigned short* __restrict__ kTp,
                                                   unsigned short* __restrict__ vTt, float* __restrict__ g){
  __shared__ short Al[64*8*8];
  __shared__ short Bl[64*8*8];
  int tid = threadIdx.x;
  int wave = tid >> 6, lane = tid & 63, l15 = lane & 15, sub = lane >> 4;
  int n0 = blockIdx.x*64, m0 = blockIdx.y*64;
  f32x4 acc[4];
  #pragma unroll
  for (int c = 0; c < 4; ++c) acc[c] = (f32x4){0.f,0.f,0.f,0.f};
  const s16x8* Ag = (const s16x8*)AB;
  const s16x8* Bg = (const s16x8*)wBt;
  s16x8* Al8 = (s16x8*)Al; s16x8* Bl8 = (s16x8*)Bl;
  for (int ks = 0; ks < 6; ++ks){
    int k0u = ks*8;
    #pragma unroll
    for (int j = 0; j < 2; ++j){
      int idx = tid*2 + j;
      int row = idx >> 3, u = idx & 7;
      Al8[row*8 + (u ^ (row & 7))] = Ag[(size_t)(m0 + row)*48 + k0u + u];
      Bl8[row*8 + (u ^ (row & 7))] = Bg[(size_t)(n0 + row)*48 + k0u + u];
    }
    __syncthreads();
    #pragma unroll
    for (int kk = 0; kk < 2; ++kk){
      int arow = wave*16 + l15;
      s16x8 af = Al8[arow*8 + ((kk*4 + sub) ^ (arow & 7))];
      #pragma unroll
      for (int c = 0; c < 4; ++c){
        int brow = c*16 + l15;
        s16x8 bf = Bl8[brow*8 + ((kk*4 + sub) ^ (brow & 7))];
        acc[c] = __builtin_amdgcn_mfma_f32_16x16x32_bf16(af, bf, acc[c], 0, 0, 0);
      }
    }
    __syncthreads();
  }
  int which = blockIdx.x / 6;
  int cb = n0 - which*384;
  if (which == 3){
    #pragma unroll
    for (int c = 0; c < 4; ++c){
      int col = cb + c*16 + l15;
      #pragma unroll
      for (int r = 0; r < 4; ++r){
        int row = m0 + wave*16 + sub*4 + r;
        float t = acc[c][r] + bg[col];
        g[(size_t)row*384 + col] = 1.f/(1.f + __expf(-t));
      }
    }
  } else if (which == 2){
    #pragma unroll
    for (int c = 0; c < 4; ++c){
      int col = cb + c*16 + l15;
      int h = col/24, d = col - h*24;
      unsigned p0 = pk_bf(acc[c][0], acc[c][1]);
      unsigned p1 = pk_bf(acc[c][2], acc[c][3]);
      size_t base = ((size_t)h*32 + d)*1024 + (size_t)(m0 + wave*16 + sub*4);
      *(uint2*)(vTt + base) = make_uint2(p0, p1);
    }
  } else {
    unsigned short* dst = which == 0 ? qTp : kTp;
    #pragma unroll
    for (int c = 0; c < 4; ++c){
      int col = cb + c*16 + l15;
      int h = col/24, d = col - h*24;
      #pragma unroll
      for (int r = 0; r < 4; ++r){
        int row = m0 + wave*16 + sub*4 + r;
        dst[((size_t)(h << 10) + row)*32 + d] = f2bf(acc[c][r]);
      }
    }
  }
}

// ---- z bias v4: LDS-free staging; mask folded; pbM in MFMA-acc layout ----
// pbM ushort idx: ((((h*16+qb)*16+kkt)*4+qg)*4+c)*256 + lane*4 + r
__global__ __launch_bounds__(256) void zbias_kernel(const float* __restrict__ z, const unsigned short* __restrict__ wwB,
                                                    const float* __restrict__ TU, const float* __restrict__ mask,
                                                    unsigned short* __restrict__ pbM){
  __shared__ float sums[64];
  __shared__ float sqs[64];
  __shared__ float accT[64][17];
  int tid = threadIdx.x;
  int wave = tid >> 6, lane = tid & 63;
  int h = lane & 15, sub = lane >> 4;
  s16x8 bfr[4];
  #pragma unroll
  for (int kc = 0; kc < 4; ++kc)
    #pragma unroll
    for (int j = 0; j < 8; ++j) bfr[kc][j] = (short)wwB[(kc*32 + sub*8 + j)*16 + h];
  s16x8 ones1;
  #pragma unroll
  for (int j = 0; j < 8; ++j) ones1[j] = (h == 0) ? (short)0x3F80 : (short)0;
  int eh = tid >> 4, epl0 = (tid & 15)*4;
  float Te = TU[eh], Ue = TU[16 + eh];
  int row = wave*16 + h;
  for (int it = 0; it < 4; ++it){
    int tile = blockIdx.x + it*4096;
    size_t pairBase = (size_t)tile*64;
    const float* zrow = z + (pairBase + row)*128;
    f32x4 acc  = {0.f, 0.f, 0.f, 0.f};
    f32x4 accS = {0.f, 0.f, 0.f, 0.f};
    f32x4 accG = {0.f, 0.f, 0.f, 0.f};
    #pragma unroll
    for (int kc = 0; kc < 4; ++kc){
      f32x4 v0 = *(const f32x4*)(zrow + kc*32 + sub*8);
      f32x4 v1 = *(const f32x4*)(zrow + kc*32 + sub*8 + 4);
      union { unsigned u[4]; s16x8 s; } cv;
      cv.u[0] = pk_bf(v0.x, v0.y); cv.u[1] = pk_bf(v0.z, v0.w);
      cv.u[2] = pk_bf(v1.x, v1.y); cv.u[3] = pk_bf(v1.z, v1.w);
      s16x8 af = cv.s;
      acc  = __builtin_amdgcn_mfma_f32_16x16x32_bf16(af, bfr[kc], acc, 0, 0, 0);
      accS = __builtin_amdgcn_mfma_f32_16x16x32_bf16(af, ones1, accS, 0, 0, 0);
      accG = __builtin_amdgcn_mfma_f32_16x16x32_bf16(af, af, accG, 0, 0, 0);
    }
    #pragma unroll
    for (int r = 0; r < 4; ++r) accT[wave*16 + sub*4 + r][h] = acc[r];
    if (h == 0){
      #pragma unroll
      for (int r = 0; r < 4; ++r) sums[wave*16 + sub*4 + r] = accS[r];
    }
    if (sub == (h >> 2)){
      int r = h & 3;
      float vq = r == 0 ? accG[0] : r == 1 ? accG[1] : r == 2 ? accG[2] : accG[3];
      sqs[wave*16 + h] = vq;
    }
    __syncthreads();
    float mus[4], rss[4];
    #pragma unroll
    for (int rr = 0; rr < 4; ++rr){
      float mu = sums[epl0+rr]*(1.f/128.f);
      float var = sqs[epl0+rr]*(1.f/128.f) - mu*mu;
      mus[rr] = mu; rss[rr] = rsqrtf(var + 1e-5f);
    }
    size_t p0 = pairBase + epl0;
    int q = (int)(p0 >> 10), k0 = (int)(p0 & 1023);
    float4 mk = *(const float4*)(mask + k0);
    float bv[4];
    bv[0] = rss[0]*(accT[epl0+0][eh] - mus[0]*Te) + Ue + 1e9f*(mk.x - 1.f);
    bv[1] = rss[1]*(accT[epl0+1][eh] - mus[1]*Te) + Ue + 1e9f*(mk.y - 1.f);
    bv[2] = rss[2]*(accT[epl0+2][eh] - mus[2]*Te) + Ue + 1e9f*(mk.z - 1.f);
    bv[3] = rss[3]*(accT[epl0+3][eh] - mus[3]*Te) + Ue + 1e9f*(mk.w - 1.f);
    int qb = q >> 6, q64 = q & 63;
    int qg = q64 >> 4, subq = (q64 >> 2) & 3, rr = q64 & 3;
    int kkt = k0 >> 6, c = (k0 >> 4) & 3, l15k = k0 & 15;
    size_t cbase = ((((size_t)(eh*16 + qb)*16 + kkt)*4 + qg)*4 + c)*256 + (size_t)rr;
    #pragma unroll
    for (int i = 0; i < 4; ++i)
      pbM[cbase + (size_t)(subq*16 + l15k + i)*4] = f2bf(bv[i]);
    __syncthreads();
  }
}

// ---- attn v7: MFMA flash. block=(qb,h), 8 waves = 4 q-groups x 2 kk-halves ----
__global__ __launch_bounds__(512) void attn_kernel(const unsigned short* __restrict__ qTp, const unsigned short* __restrict__ kTp,
                                                   const unsigned short* __restrict__ vTt, const unsigned short* __restrict__ pbM,
                                                   const float* __restrict__ g, unsigned short* __restrict__ ogB){
  __shared__ float lds[8192];          // 8 waves x 1024 floats; per-wave: P tile (2KB) / combine (4KB)
  int tid = threadIdx.x;
  int wave = tid >> 6, lane = tid & 63, l15 = lane & 15, sub = lane >> 4;
  int qb = blockIdx.x, h = blockIdx.y;
  int qg = wave & 3, half = wave >> 2;
  int qrow = qb*64 + qg*16 + l15;
  s16x8 qf = *(const s16x8*)(qTp + ((size_t)(h << 10) + qrow)*32 + sub*8);
  f32x4 o0 = {0.f,0.f,0.f,0.f}, o1 = {0.f,0.f,0.f,0.f};
  float m[4] = {-1e30f,-1e30f,-1e30f,-1e30f}, l[4] = {0.f,0.f,0.f,0.f};
  char* Pb = (char*)(lds + wave*1024);
  const unsigned short* kBase = kTp + ((size_t)(h << 10))*32;
  const unsigned short* vBase = vTt + (size_t)h*32*1024;
  const unsigned short* pbW = pbM + (size_t)(h*16 + qb)*16*4096 + (size_t)qg*1024 + (size_t)lane*4;
  for (int t = 0; t < 8; ++t){
    int kkt = half*8 + t;
    int kk0 = kkt*64;
    f32x4 s[4];
    #pragma unroll
    for (int c = 0; c < 4; ++c){
      s16x8 kf = *(const s16x8*)(kBase + (size_t)(kk0 + c*16 + l15)*32 + sub*8);
      s[c] = __builtin_amdgcn_mfma_f32_16x16x32_bf16(qf, kf, (f32x4){0.f,0.f,0.f,0.f}, 0, 0, 0);
    }
    const unsigned short* pbt = pbW + (size_t)kkt*4096;
    #pragma unroll
    for (int c = 0; c < 4; ++c){
      uint2 pv = *(const uint2*)(pbt + c*256);
      s[c][0] += bf2f((unsigned short)(pv.x & 0xffff));
      s[c][1] += bf2f((unsigned short)(pv.x >> 16));
      s[c][2] += bf2f((unsigned short)(pv.y & 0xffff));
      s[c][3] += bf2f((unsigned short)(pv.y >> 16));
    }
    #pragma unroll
    for (int r = 0; r < 4; ++r){
      float pm = fmaxf(fmaxf(s[0][r], s[1][r]), fmaxf(s[2][r], s[3][r]));
      pm = fmaxf(pm, __shfl_xor(pm, 1));
      pm = fmaxf(pm, __shfl_xor(pm, 2));
      pm = fmaxf(pm, __shfl_xor(pm, 4));
      pm = fmaxf(pm, __shfl_xor(pm, 8));
      float mn = fmaxf(m[r], pm);
      float corr = __expf(m[r] - mn);
      m[r] = mn;
      float ps = 0.f;
      #pragma unroll
      for (int c = 0; c < 4; ++c){ s[c][r] = __expf(s[c][r] - mn); ps += s[c][r]; }
      ps += __shfl_xor(ps, 1); ps += __shfl_xor(ps, 2);
      ps += __shfl_xor(ps, 4); ps += __shfl_xor(ps, 8);
      l[r] = l[r]*corr + ps;
      o0[r] *= corr; o1[r] *= corr;
    }
    // P -> LDS bf16, XOR-swizzled: row q = sub*4+r, col kk = c*16+l15
    #pragma unroll
    for (int c = 0; c < 4; ++c){
      #pragma unroll
      for (int r = 0; r < 4; ++r){
        int qq = sub*4 + r;
        int byte = ((qq*128 + (c*16 + l15)*2)) ^ ((qq & 7) << 4);
        *(short*)(Pb + byte) = (short)f2bf(s[c][r]);
      }
    }
    // PV: A = P rows (q=l15), B = V^T
    #pragma unroll
    for (int kh = 0; kh < 2; ++kh){
      int byteA = (l15*128 + kh*64 + sub*16) ^ ((l15 & 7) << 4);
      s16x8 pa = *(const s16x8*)(Pb + byteA);
      s16x8 vb0 = *(const s16x8*)(vBase + (size_t)l15*1024 + kk0 + kh*32 + sub*8);
      s16x8 vb1 = *(const s16x8*)(vBase + (size_t)(16 + l15)*1024 + kk0 + kh*32 + sub*8);
      o0 = __builtin_amdgcn_mfma_f32_16x16x32_bf16(pa, vb0, o0, 0, 0, 0);
      o1 = __builtin_amdgcn_mfma_f32_16x16x32_bf16(pa, vb1, o1, 0, 0, 0);
    }
  }
  // ---- combine halves (wave w with w+4) ----
  {
    float* cw = lds + wave*1024 + lane*16;
    cw[0] = o0[0]; cw[1] = o0[1]; cw[2] = o0[2]; cw[3] = o0[3];
    cw[4] = o1[0]; cw[5] = o1[1]; cw[6] = o1[2]; cw[7] = o1[3];
    cw[8] = m[0]; cw[9] = m[1]; cw[10] = m[2]; cw[11] = m[3];
    cw[12] = l[0]; cw[13] = l[1]; cw[14] = l[2]; cw[15] = l[3];
  }
  __syncthreads();
  if (wave < 4){
    const float* c2 = lds + (wave + 4)*1024 + lane*16;
    #pragma unroll
    for (int r = 0; r < 4; ++r){
      float m2 = c2[8 + r], l2 = c2[12 + r];
      float nm = fmaxf(m[r], m2);
      float f1 = __expf(m[r] - nm), f2 = __expf(m2 - nm);
      float L = l[r]*f1 + l2*f2;
      float O0 = o0[r]*f1 + c2[r]*f2;
      float O1 = o1[r]*f1 + c2[4 + r]*f2;
      float inv = 1.f/L;
      int q = qb*64 + qg*16 + sub*4 + r;
      size_t base = (size_t)q*384 + h*24;
      ogB[base + l15] = f2bf(g[base + l15]*O0*inv);
      if (l15 < 8) ogB[base + 16 + l15] = f2bf(g[base + 16 + l15]*O1*inv);
    }
  }
}

// ---- final projection: ogB[1024x384]bf16 @ wo^T bf16 via MFMA, + bo ----
__global__ __launch_bounds__(256) void gemm_out(const unsigned short* __restrict__ AB,
                                                const unsigned short* __restrict__ wBo,
                                                const float* __restrict__ bo, float* __restrict__ dst){
  __shared__ short Al[64*8*8];
  __shared__ short Bl[64*8*8];
  int tid = threadIdx.x;
  int wave = tid >> 6, lane = tid & 63, l15 = lane & 15, sub = lane >> 4;
  int n0 = blockIdx.x*64, m0 = blockIdx.y*64;
  f32x4 acc[4];
  #pragma unroll
  for (int c = 0; c < 4; ++c) acc[c] = (f32x4){0.f,0.f,0.f,0.f};
  const s16x8* Ag = (const s16x8*)AB;
  const s16x8* Bg = (const s16x8*)wBo;
  s16x8* Al8 = (s16x8*)Al; s16x8* Bl8 = (s16x8*)Bl;
  for (int ks = 0; ks < 6; ++ks){
    int k0u = ks*8;
    #pragma unroll
    for (int j = 0; j < 2; ++j){
      int idx = tid*2 + j;
      int row = idx >> 3, u = idx & 7;
      Al8[row*8 + (u ^ (row & 7))] = Ag[(size_t)(m0 + row)*48 + k0u + u];
      Bl8[row*8 + (u ^ (row & 7))] = Bg[(size_t)(n0 + row)*48 + k0u + u];
    }
    __syncthreads();
    #pragma unroll
    for (int kk = 0; kk < 2; ++kk){
      int arow = wave*16 + l15;
      s16x8 af = Al8[arow*8 + ((kk*4 + sub) ^ (arow & 7))];
      #pragma unroll
      for (int c = 0; c < 4; ++c){
        int brow = c*16 + l15;
        s16x8 bf = Bl8[brow*8 + ((kk*4 + sub) ^ (brow & 7))];
        acc[c] = __builtin_amdgcn_mfma_f32_16x16x32_bf16(af, bf, acc[c], 0, 0, 0);
      }
    }
    __syncthreads();
  }
  #pragma unroll
  for (int c = 0; c < 4; ++c){
    int col = n0 + c*16 + l15;
    float b = bo[col];
    #pragma unroll
    for (int r = 0; r < 4; ++r){
      int row = m0 + wave*16 + sub*4 + r;
      dst[(size_t)row*384 + col] = acc[c][r] + b;
    }
  }
}

extern "C" void kernel_launch(void* const* d_in, const int* in_sizes, int n_in,
                              void* d_out, int out_size, void* d_ws, size_t ws_size,
                              hipStream_t stream){
  const float* a      = (const float*)d_in[0];
  const float* z      = (const float*)d_in[1];
  const float* mask   = (const float*)d_in[2];
  const float* ln_a_w = (const float*)d_in[3];
  const float* ln_a_b = (const float*)d_in[4];
  const float* ln_z_w = (const float*)d_in[5];
  const float* ln_z_b = (const float*)d_in[6];
  const float* w_z    = (const float*)d_in[7];
  const float* wq     = (const float*)d_in[8];
  const float* wk     = (const float*)d_in[9];
  const float* wv     = (const float*)d_in[10];
  const float* wg     = (const float*)d_in[11];
  const float* bg     = (const float*)d_in[12];
  const float* wo     = (const float*)d_in[13];
  const float* bo     = (const float*)d_in[14];

  char* ws = (char*)d_ws;
  unsigned short* a_lnB = (unsigned short*)(ws + ((size_t)0u));
  unsigned short* wBall = (unsigned short*)(ws + ((size_t)1u << 20));
  unsigned short* qTp   = (unsigned short*)(ws + ((size_t)4u << 20));
  unsigned short* kTp   = (unsigned short*)(ws + ((size_t)6u << 20));
  unsigned short* vTt   = (unsigned short*)(ws + ((size_t)8u << 20));
  float* g    = (float*)(ws + ((size_t)10u << 20));
  unsigned short* ogB = (unsigned short*)(ws + ((size_t)12u << 20));
  unsigned short* wwB = (unsigned short*)(ws + ((size_t)14u << 20));
  float* TU   = (float*)(ws + ((size_t)14u << 20) + 8192);
  unsigned short* pbM = (unsigned short*)(ws + ((size_t)24u << 20));

  hipLaunchKernelGGL(prep_kernel, dim3(629), dim3(256), 0, stream, a, ln_a_w, ln_a_b,
                     ln_z_w, ln_z_b, w_z, wq, wk, wv, wg, wo, a_lnB, wBall, wwB, TU, qTp, kTp, vTt);
  hipLaunchKernelGGL(qkvg_kernel, dim3(24,16), dim3(256), 0, stream, a_lnB, wBall, bg, qTp, kTp, vTt, g);
  hipLaunchKernelGGL(zbias_kernel, dim3(4096), dim3(256), 0, stream, z, wwB, TU, mask, pbM);
  hipLaunchKernelGGL(attn_kernel, dim3(16,16), dim3(512), 0, stream, qTp, kTp, vTt, pbM, g, ogB);
  hipLaunchKernelGGL(gemm_out, dim3(6,16), dim3(256), 0, stream, ogB, wBall + (size_t)4*384*384, bo, (float*)d_out);
}

// Round 12
// 173.573 us; speedup vs baseline: 11.6655x; 1.0017x over previous
//
#include <hip/hip_runtime.h>
#include <hip/hip_bf16.h>

typedef float f32x4 __attribute__((ext_vector_type(4)));
typedef short s16x8 __attribute__((ext_vector_type(8)));

__device__ __forceinline__ unsigned short f2bf(float x){
  unsigned u = __float_as_uint(x);
  u += 0x7fffu + ((u >> 16) & 1u);
  return (unsigned short)(u >> 16);
}
__device__ __forceinline__ float bf2f(unsigned short h){
  return __uint_as_float(((unsigned)h) << 16);
}
__device__ __forceinline__ unsigned pk_bf(float a, float b){
  __hip_bfloat162 t = __float22bfloat162_rn(make_float2(a, b));
  return *reinterpret_cast<unsigned*>(&t);
}

// ---- prep: weight transpose->bf16 (0..179), ln_a (180..435), setup (436), zero-pads (437..628) ----
__global__ __launch_bounds__(256) void prep_kernel(const float* __restrict__ a, const float* __restrict__ ln_a_w,
                             const float* __restrict__ ln_a_b, const float* __restrict__ lnzw,
                             const float* __restrict__ lnzb, const float* __restrict__ w_z,
                             const float* __restrict__ wq, const float* __restrict__ wk,
                             const float* __restrict__ wv, const float* __restrict__ wg,
                             const float* __restrict__ wo,
                             unsigned short* __restrict__ a_lnB, unsigned short* __restrict__ wBall,
                             unsigned short* __restrict__ wwB, float* __restrict__ TU,
                             unsigned short* __restrict__ qTp, unsigned short* __restrict__ kTp,
                             unsigned short* __restrict__ vTt){
  int bid = blockIdx.x, tid = threadIdx.x;
  if (bid < 180){
    __shared__ float t[64][65];
    int mat = bid/36, tt = bid - mat*36;
    int c0 = (tt % 6)*64, k0 = (tt / 6)*64;
    const float* src = mat == 0 ? wq : mat == 1 ? wk : mat == 2 ? wv : mat == 3 ? wg : wo;
    int r = tid >> 4, c4 = (tid & 15)*4;
    #pragma unroll
    for (int rr = 0; rr < 4; ++rr){
      float4 v = *(const float4*)(src + (size_t)(k0 + r + rr*16)*384 + c0 + c4);
      t[r + rr*16][c4+0] = v.x; t[r + rr*16][c4+1] = v.y;
      t[r + rr*16][c4+2] = v.z; t[r + rr*16][c4+3] = v.w;
    }
    __syncthreads();
    float scale = (mat == 0) ? 0.20412414523193154f : 1.f;
    int cc = tid >> 2, kp = (tid & 3)*16;
    unsigned ow[8];
    #pragma unroll
    for (int j = 0; j < 8; ++j)
      ow[j] = pk_bf(t[kp + 2*j][cc]*scale, t[kp + 2*j + 1][cc]*scale);
    unsigned short* dst = wBall + ((size_t)(mat*384 + c0 + cc)*384 + k0 + kp);
    *(uint4*)dst       = make_uint4(ow[0], ow[1], ow[2], ow[3]);
    *(uint4*)(dst + 8) = make_uint4(ow[4], ow[5], ow[6], ow[7]);
  } else if (bid < 436){
    int r = (bid - 180)*4 + (tid >> 6), l = tid & 63;
    const float* ap = a + (size_t)r*384;
    float x[6]; float s = 0.f, sq = 0.f;
    #pragma unroll
    for (int i = 0; i < 6; ++i){ x[i] = ap[i*64 + l]; s += x[i]; sq += x[i]*x[i]; }
    #pragma unroll
    for (int off = 32; off; off >>= 1){ s += __shfl_xor(s, off); sq += __shfl_xor(sq, off); }
    float mu = s*(1.f/384.f);
    float var = sq*(1.f/384.f) - mu*mu;
    float rs = rsqrtf(var + 1e-5f);
    #pragma unroll
    for (int i = 0; i < 6; ++i){ int c = i*64 + l; a_lnB[(size_t)r*384 + c] = f2bf((x[i]-mu)*rs*ln_a_w[c] + ln_a_b[c]); }
  } else if (bid == 436){
    if (tid < 128){
      float lw = lnzw[tid];
      #pragma unroll
      for (int h = 0; h < 16; ++h) wwB[tid*16 + h] = f2bf(lw * w_z[tid*16 + h]);
    }
    if (tid < 16){
      float T = 0.f, U = 0.f;
      for (int c = 0; c < 128; ++c){ T += lnzw[c]*w_z[c*16 + tid]; U += lnzb[c]*w_z[c*16 + tid]; }
      TU[tid] = T; TU[16 + tid] = U;
    }
  } else {
    int t = (bid - 437)*256 + tid;       // 0..49151
    uint4 zv = make_uint4(0,0,0,0);
    if (t < 16384)      *(uint4*)(qTp + (size_t)t*32 + 24) = zv;
    else if (t < 32768) *(uint4*)(kTp + (size_t)(t - 16384)*32 + 24) = zv;
    else {
      int t2 = t - 32768;                 // 0..16383
      int h = t2 >> 10, w = t2 & 1023;
      *(uint4*)(vTt + ((size_t)h*32 + 24)*1024 + (size_t)w*8) = zv;
    }
  }
}

// ---- fused mid: blocks 0..383 = QKVG MFMA; blocks 384..4479 = zbias ----
__global__ __launch_bounds__(256) void midfuse_kernel(const unsigned short* __restrict__ AB,
                                                      const unsigned short* __restrict__ wBt,
                                                      const float* __restrict__ bg,
                                                      unsigned short* __restrict__ qTp, unsigned short* __restrict__ kTp,
                                                      unsigned short* __restrict__ vTt, float* __restrict__ g,
                                                      const float* __restrict__ z, const unsigned short* __restrict__ wwB,
                                                      const float* __restrict__ TU, const float* __restrict__ mask,
                                                      unsigned short* __restrict__ pbM){
  __shared__ char smem[16384];
  int bid = blockIdx.x, tid = threadIdx.x;
  int wave = tid >> 6, lane = tid & 63, l15 = lane & 15, sub = lane >> 4;
  if (bid < 384){
    // ---------------- QKVG ----------------
    s16x8* Al8 = (s16x8*)smem;
    s16x8* Bl8 = (s16x8*)(smem + 8192);
    int bx = bid % 24, by = bid / 24;
    int n0 = bx*64, m0 = by*64;
    f32x4 acc[4];
    #pragma unroll
    for (int c = 0; c < 4; ++c) acc[c] = (f32x4){0.f,0.f,0.f,0.f};
    const s16x8* Ag = (const s16x8*)AB;
    const s16x8* Bg = (const s16x8*)wBt;
    for (int ks = 0; ks < 6; ++ks){
      int k0u = ks*8;
      #pragma unroll
      for (int j = 0; j < 2; ++j){
        int idx = tid*2 + j;
        int row = idx >> 3, u = idx & 7;
        Al8[row*8 + (u ^ (row & 7))] = Ag[(size_t)(m0 + row)*48 + k0u + u];
        Bl8[row*8 + (u ^ (row & 7))] = Bg[(size_t)(n0 + row)*48 + k0u + u];
      }
      __syncthreads();
      #pragma unroll
      for (int kk = 0; kk < 2; ++kk){
        int arow = wave*16 + l15;
        s16x8 af = Al8[arow*8 + ((kk*4 + sub) ^ (arow & 7))];
        #pragma unroll
        for (int c = 0; c < 4; ++c){
          int brow = c*16 + l15;
          s16x8 bf = Bl8[brow*8 + ((kk*4 + sub) ^ (brow & 7))];
          acc[c] = __builtin_amdgcn_mfma_f32_16x16x32_bf16(af, bf, acc[c], 0, 0, 0);
        }
      }
      __syncthreads();
    }
    int which = bx / 6;
    int cb = n0 - which*384;
    if (which == 3){
      #pragma unroll
      for (int c = 0; c < 4; ++c){
        int col = cb + c*16 + l15;
        #pragma unroll
        for (int r = 0; r < 4; ++r){
          int row = m0 + wave*16 + sub*4 + r;
          float t = acc[c][r] + bg[col];
          g[(size_t)row*384 + col] = 1.f/(1.f + __expf(-t));
        }
      }
    } else if (which == 2){
      #pragma unroll
      for (int c = 0; c < 4; ++c){
        int col = cb + c*16 + l15;
        int h = col/24, d = col - h*24;
        unsigned p0 = pk_bf(acc[c][0], acc[c][1]);
        unsigned p1 = pk_bf(acc[c][2], acc[c][3]);
        size_t base = ((size_t)h*32 + d)*1024 + (size_t)(m0 + wave*16 + sub*4);
        *(uint2*)(vTt + base) = make_uint2(p0, p1);
      }
    } else {
      unsigned short* dst = which == 0 ? qTp : kTp;
      #pragma unroll
      for (int c = 0; c < 4; ++c){
        int col = cb + c*16 + l15;
        int h = col/24, d = col - h*24;
        #pragma unroll
        for (int r = 0; r < 4; ++r){
          int row = m0 + wave*16 + sub*4 + r;
          dst[((size_t)(h << 10) + row)*32 + d] = f2bf(acc[c][r]);
        }
      }
    }
  } else {
    // ---------------- zbias ----------------
    float* sums = (float*)smem;
    float* sqs  = sums + 64;
    float (*accT)[17] = (float(*)[17])(sqs + 64);
    int tb = bid - 384;
    int h = l15, subz = sub;
    s16x8 bfr[4];
    #pragma unroll
    for (int kc = 0; kc < 4; ++kc)
      #pragma unroll
      for (int j = 0; j < 8; ++j) bfr[kc][j] = (short)wwB[(kc*32 + subz*8 + j)*16 + h];
    s16x8 ones1;
    #pragma unroll
    for (int j = 0; j < 8; ++j) ones1[j] = (h == 0) ? (short)0x3F80 : (short)0;
    int eh = tid >> 4, epl0 = (tid & 15)*4;
    float Te = TU[eh], Ue = TU[16 + eh];
    int row = wave*16 + h;
    for (int it = 0; it < 4; ++it){
      int tile = tb + it*4096;
      size_t pairBase = (size_t)tile*64;
      const float* zrow = z + (pairBase + row)*128;
      f32x4 acc  = {0.f, 0.f, 0.f, 0.f};
      f32x4 accS = {0.f, 0.f, 0.f, 0.f};
      f32x4 accG = {0.f, 0.f, 0.f, 0.f};
      #pragma unroll
      for (int kc = 0; kc < 4; ++kc){
        f32x4 v0 = *(const f32x4*)(zrow + kc*32 + subz*8);
        f32x4 v1 = *(const f32x4*)(zrow + kc*32 + subz*8 + 4);
        union { unsigned u[4]; s16x8 s; } cv;
        cv.u[0] = pk_bf(v0.x, v0.y); cv.u[1] = pk_bf(v0.z, v0.w);
        cv.u[2] = pk_bf(v1.x, v1.y); cv.u[3] = pk_bf(v1.z, v1.w);
        s16x8 af = cv.s;
        acc  = __builtin_amdgcn_mfma_f32_16x16x32_bf16(af, bfr[kc], acc, 0, 0, 0);
        accS = __builtin_amdgcn_mfma_f32_16x16x32_bf16(af, ones1, accS, 0, 0, 0);
        accG = __builtin_amdgcn_mfma_f32_16x16x32_bf16(af, af, accG, 0, 0, 0);
      }
      #pragma unroll
      for (int r = 0; r < 4; ++r) accT[wave*16 + subz*4 + r][h] = acc[r];
      if (h == 0){
        #pragma unroll
        for (int r = 0; r < 4; ++r) sums[wave*16 + subz*4 + r] = accS[r];
      }
      if (subz == (h >> 2)){
        int r = h & 3;
        float vq = r == 0 ? accG[0] : r == 1 ? accG[1] : r == 2 ? accG[2] : accG[3];
        sqs[wave*16 + h] = vq;
      }
      __syncthreads();
      float mus[4], rss[4];
      #pragma unroll
      for (int rr = 0; rr < 4; ++rr){
        float mu = sums[epl0+rr]*(1.f/128.f);
        float var = sqs[epl0+rr]*(1.f/128.f) - mu*mu;
        mus[rr] = mu; rss[rr] = rsqrtf(var + 1e-5f);
      }
      size_t p0 = pairBase + epl0;
      int q = (int)(p0 >> 10), k0 = (int)(p0 & 1023);
      float4 mk = *(const float4*)(mask + k0);
      float bv[4];
      bv[0] = rss[0]*(accT[epl0+0][eh] - mus[0]*Te) + Ue + 1e9f*(mk.x - 1.f);
      bv[1] = rss[1]*(accT[epl0+1][eh] - mus[1]*Te) + Ue + 1e9f*(mk.y - 1.f);
      bv[2] = rss[2]*(accT[epl0+2][eh] - mus[2]*Te) + Ue + 1e9f*(mk.z - 1.f);
      bv[3] = rss[3]*(accT[epl0+3][eh] - mus[3]*Te) + Ue + 1e9f*(mk.w - 1.f);
      int qb = q >> 6, q64 = q & 63;
      int qg = q64 >> 4, subq = (q64 >> 2) & 3, rr2 = q64 & 3;
      int kkt = k0 >> 6, c = (k0 >> 4) & 3, l15k = k0 & 15;
      size_t cbase = ((((size_t)(eh*16 + qb)*16 + kkt)*4 + qg)*4 + c)*256 + (size_t)rr2;
      #pragma unroll
      for (int i = 0; i < 4; ++i)
        pbM[cbase + (size_t)(subq*16 + l15k + i)*4] = f2bf(bv[i]);
      __syncthreads();
    }
  }
}

// ---- attn v8: MFMA flash. block=(qb32,h) 512 blocks, 8 waves = 2 q-groups x 4 kk-quarters ----
__global__ __launch_bounds__(512) void attn_kernel(const unsigned short* __restrict__ qTp, const unsigned short* __restrict__ kTp,
                                                   const unsigned short* __restrict__ vTt, const unsigned short* __restrict__ pbM,
                                                   const float* __restrict__ g, unsigned short* __restrict__ ogB){
  __shared__ float lds[8192];          // 8 waves x 1024 floats: P tile / state
  int tid = threadIdx.x;
  int wave = tid >> 6, lane = tid & 63, l15 = lane & 15, sub = lane >> 4;
  int qb32 = blockIdx.x, h = blockIdx.y;
  int qg_l = wave & 1, kkq = wave >> 1;
  int qrow = qb32*32 + qg_l*16 + l15;
  s16x8 qf = *(const s16x8*)(qTp + ((size_t)(h << 10) + qrow)*32 + sub*8);
  f32x4 o0 = {0.f,0.f,0.f,0.f}, o1 = {0.f,0.f,0.f,0.f};
  float m[4] = {-1e30f,-1e30f,-1e30f,-1e30f}, l[4] = {0.f,0.f,0.f,0.f};
  char* Pb = (char*)(lds + wave*1024);
  const unsigned short* kBase = kTp + ((size_t)(h << 10))*32;
  const unsigned short* vBase = vTt + (size_t)h*32*1024;
  int qb64 = qb32 >> 1, qg4 = (qb32 & 1)*2 + qg_l;
  const unsigned short* pbW = pbM + (size_t)(h*16 + qb64)*16*4096 + (size_t)qg4*1024 + (size_t)lane*4;
  for (int t = 0; t < 4; ++t){
    int kkt = kkq*4 + t;
    int kk0 = kkt*64;
    const unsigned short* pbt = pbW + (size_t)kkt*4096;
    uint2 pv0 = *(const uint2*)(pbt + 0);
    uint2 pv1 = *(const uint2*)(pbt + 256);
    uint2 pv2 = *(const uint2*)(pbt + 512);
    uint2 pv3 = *(const uint2*)(pbt + 768);
    f32x4 s[4];
    #pragma unroll
    for (int c = 0; c < 4; ++c){
      s16x8 kf = *(const s16x8*)(kBase + (size_t)(kk0 + c*16 + l15)*32 + sub*8);
      s[c] = __builtin_amdgcn_mfma_f32_16x16x32_bf16(qf, kf, (f32x4){0.f,0.f,0.f,0.f}, 0, 0, 0);
    }
    {
      uint2 pv[4] = {pv0, pv1, pv2, pv3};
      #pragma unroll
      for (int c = 0; c < 4; ++c){
        s[c][0] += bf2f((unsigned short)(pv[c].x & 0xffff));
        s[c][1] += bf2f((unsigned short)(pv[c].x >> 16));
        s[c][2] += bf2f((unsigned short)(pv[c].y & 0xffff));
        s[c][3] += bf2f((unsigned short)(pv[c].y >> 16));
      }
    }
    #pragma unroll
    for (int r = 0; r < 4; ++r){
      float pm = fmaxf(fmaxf(s[0][r], s[1][r]), fmaxf(s[2][r], s[3][r]));
      pm = fmaxf(pm, __shfl_xor(pm, 1));
      pm = fmaxf(pm, __shfl_xor(pm, 2));
      pm = fmaxf(pm, __shfl_xor(pm, 4));
      pm = fmaxf(pm, __shfl_xor(pm, 8));
      float mn = fmaxf(m[r], pm);
      float corr = __expf(m[r] - mn);
      m[r] = mn;
      float ps = 0.f;
      #pragma unroll
      for (int c = 0; c < 4; ++c){ s[c][r] = __expf(s[c][r] - mn); ps += s[c][r]; }
      ps += __shfl_xor(ps, 1); ps += __shfl_xor(ps, 2);
      ps += __shfl_xor(ps, 4); ps += __shfl_xor(ps, 8);
      l[r] = l[r]*corr + ps;
      o0[r] *= corr; o1[r] *= corr;
    }
    // P -> LDS bf16, XOR-swizzled: row q = sub*4+r, col kk = c*16+l15
    #pragma unroll
    for (int c = 0; c < 4; ++c){
      #pragma unroll
      for (int r = 0; r < 4; ++r){
        int qq = sub*4 + r;
        int byte = ((qq*128 + (c*16 + l15)*2)) ^ ((qq & 7) << 4);
        *(short*)(Pb + byte) = (short)f2bf(s[c][r]);
      }
    }
    // PV: A = P rows (q=l15), B = V^T
    #pragma unroll
    for (int kh = 0; kh < 2; ++kh){
      int byteA = (l15*128 + kh*64 + sub*16) ^ ((l15 & 7) << 4);
      s16x8 pa = *(const s16x8*)(Pb + byteA);
      s16x8 vb0 = *(const s16x8*)(vBase + (size_t)l15*1024 + kk0 + kh*32 + sub*8);
      s16x8 vb1 = *(const s16x8*)(vBase + (size_t)(16 + l15)*1024 + kk0 + kh*32 + sub*8);
      o0 = __builtin_amdgcn_mfma_f32_16x16x32_bf16(pa, vb0, o0, 0, 0, 0);
      o1 = __builtin_amdgcn_mfma_f32_16x16x32_bf16(pa, vb1, o1, 0, 0, 0);
    }
  }
  // ---- write per-wave state, combine 4 kk-quarters per q-group ----
  {
    float* cw = lds + wave*1024 + lane*16;
    cw[0] = o0[0]; cw[1] = o0[1]; cw[2] = o0[2]; cw[3] = o0[3];
    cw[4] = o1[0]; cw[5] = o1[1]; cw[6] = o1[2]; cw[7] = o1[3];
    cw[8] = m[0]; cw[9] = m[1]; cw[10] = m[2]; cw[11] = m[3];
    cw[12] = l[0]; cw[13] = l[1]; cw[14] = l[2]; cw[15] = l[3];
  }
  __syncthreads();
  if (kkq == 0){
    #pragma unroll
    for (int k2 = 1; k2 < 4; ++k2){
      const float* c2 = lds + (size_t)(k2*2 + qg_l)*1024 + lane*16;
      #pragma unroll
      for (int r = 0; r < 4; ++r){
        float m2 = c2[8 + r], l2 = c2[12 + r];
        float nm = fmaxf(m[r], m2);
        float f1 = __expf(m[r] - nm), f2 = __expf(m2 - nm);
        l[r] = l[r]*f1 + l2*f2;
        o0[r] = o0[r]*f1 + c2[r]*f2;
        o1[r] = o1[r]*f1 + c2[4 + r]*f2;
        m[r] = nm;
      }
    }
    #pragma unroll
    for (int r = 0; r < 4; ++r){
      float inv = 1.f/l[r];
      int q = qb32*32 + qg_l*16 + sub*4 + r;
      size_t base = (size_t)q*384 + h*24;
      ogB[base + l15] = f2bf(g[base + l15]*o0[r]*inv);
      if (l15 < 8) ogB[base + 16 + l15] = f2bf(g[base + 16 + l15]*o1[r]*inv);
    }
  }
}

// ---- final projection: ogB[1024x384]bf16 @ wo^T bf16 via MFMA, + bo ----
__global__ __launch_bounds__(256) void gemm_out(const unsigned short* __restrict__ AB,
                                                const unsigned short* __restrict__ wBo,
                                                const float* __restrict__ bo, float* __restrict__ dst){
  __shared__ short Al[64*8*8];
  __shared__ short Bl[64*8*8];
  int tid = threadIdx.x;
  int wave = tid >> 6, lane = tid & 63, l15 = lane & 15, sub = lane >> 4;
  int n0 = blockIdx.x*64, m0 = blockIdx.y*64;
  f32x4 acc[4];
  #pragma unroll
  for (int c = 0; c < 4; ++c) acc[c] = (f32x4){0.f,0.f,0.f,0.f};
  const s16x8* Ag = (const s16x8*)AB;
  const s16x8* Bg = (const s16x8*)wBo;
  s16x8* Al8 = (s16x8*)Al; s16x8* Bl8 = (s16x8*)Bl;
  for (int ks = 0; ks < 6; ++ks){
    int k0u = ks*8;
    #pragma unroll
    for (int j = 0; j < 2; ++j){
      int idx = tid*2 + j;
      int row = idx >> 3, u = idx & 7;
      Al8[row*8 + (u ^ (row & 7))] = Ag[(size_t)(m0 + row)*48 + k0u + u];
      Bl8[row*8 + (u ^ (row & 7))] = Bg[(size_t)(n0 + row)*48 + k0u + u];
    }
    __syncthreads();
    #pragma unroll
    for (int kk = 0; kk < 2; ++kk){
      int arow = wave*16 + l15;
      s16x8 af = Al8[arow*8 + ((kk*4 + sub) ^ (arow & 7))];
      #pragma unroll
      for (int c = 0; c < 4; ++c){
        int brow = c*16 + l15;
        s16x8 bf = Bl8[brow*8 + ((kk*4 + sub) ^ (brow & 7))];
        acc[c] = __builtin_amdgcn_mfma_f32_16x16x32_bf16(af, bf, acc[c], 0, 0, 0);
      }
    }
    __syncthreads();
  }
  #pragma unroll
  for (int c = 0; c < 4; ++c){
    int col = n0 + c*16 + l15;
    float b = bo[col];
    #pragma unroll
    for (int r = 0; r < 4; ++r){
      int row = m0 + wave*16 + sub*4 + r;
      dst[(size_t)row*384 + col] = acc[c][r] + b;
    }
  }
}

extern "C" void kernel_launch(void* const* d_in, const int* in_sizes, int n_in,
                              void* d_out, int out_size, void* d_ws, size_t ws_size,
                              hipStream_t stream){
  const float* a      = (const float*)d_in[0];
  const float* z      = (const float*)d_in[1];
  const float* mask   = (const float*)d_in[2];
  const float* ln_a_w = (const float*)d_in[3];
  const float* ln_a_b = (const float*)d_in[4];
  const float* ln_z_w = (const float*)d_in[5];
  const float* ln_z_b = (const float*)d_in[6];
  const float* w_z    = (const float*)d_in[7];
  const float* wq     = (const float*)d_in[8];
  const float* wk     = (const float*)d_in[9];
  const float* wv     = (const float*)d_in[10];
  const float* wg     = (const float*)d_in[11];
  const float* bg     = (const float*)d_in[12];
  const float* wo     = (const float*)d_in[13];
  const float* bo     = (const float*)d_in[14];

  char* ws = (char*)d_ws;
  unsigned short* a_lnB = (unsigned short*)(ws + ((size_t)0u));
  unsigned short* wBall = (unsigned short*)(ws + ((size_t)1u << 20));
  unsigned short* qTp   = (unsigned short*)(ws + ((size_t)4u << 20));
  unsigned short* kTp   = (unsigned short*)(ws + ((size_t)6u << 20));
  unsigned short* vTt   = (unsigned short*)(ws + ((size_t)8u << 20));
  float* g    = (float*)(ws + ((size_t)10u << 20));
  unsigned short* ogB = (unsigned short*)(ws + ((size_t)12u << 20));
  unsigned short* wwB = (unsigned short*)(ws + ((size_t)14u << 20));
  float* TU   = (float*)(ws + ((size_t)14u << 20) + 8192);
  unsigned short* pbM = (unsigned short*)(ws + ((size_t)24u << 20));

  hipLaunchKernelGGL(prep_kernel, dim3(629), dim3(256), 0, stream, a, ln_a_w, ln_a_b,
                     ln_z_w, ln_z_b, w_z, wq, wk, wv, wg, wo, a_lnB, wBall, wwB, TU, qTp, kTp, vTt);
  hipLaunchKernelGGL(midfuse_kernel, dim3(4480), dim3(256), 0, stream, a_lnB, wBall, bg,
                     qTp, kTp, vTt, g, z, wwB, TU, mask, pbM);
  hipLaunchKernelGGL(attn_kernel, dim3(32,16), dim3(512), 0, stream, qTp, kTp, vTt, pbM, g, ogB);
  hipLaunchKernelGGL(gemm_out, dim3(6,16), dim3(256), 0, stream, ogB, wBall + (size_t)4*384*384, bo, (float*)d_out);
}